// Round 16
// baseline (107.262 us; speedup 1.0000x reference)
//
#include <hip/hip_runtime.h>

#define N_ 256
#define L_ 4096
#define DM_ 2048
#define STEPF (1.0f / 4096.0f)
#define NW 15   // W-side Taylor terms: ||0.984*A||~2 -> 2^15/15! ~ 2.5e-8 (K rel-err << bf16)
#define NV 6    // V-side Taylor terms
#define RQN 4608

typedef short bf16x8 __attribute__((ext_vector_type(8)));
typedef float f32x4 __attribute__((ext_vector_type(4)));
typedef unsigned int uint32;

__device__ __forceinline__ uint32 bf16rne(float f) {
    uint32 u = __builtin_bit_cast(uint32, f);
    return (u + 0x7FFFu + ((u >> 16) & 1u)) >> 16;
}
__device__ __forceinline__ float rdlane(float v, int l) {
    return __builtin_bit_cast(float, __builtin_amdgcn_readlane(__builtin_bit_cast(int, v), l));
}
__device__ __forceinline__ float hif(float x) {   // bf16-truncated high part
    return __builtin_bit_cast(float, __builtin_bit_cast(uint32, x) & 0xFFFF0000u);
}
// pack 2 f32 -> 2 bf16 (truncate) in one v_perm: dst = {LO.hi16, HI.hi16}
#define PK2(LO, HI) __builtin_amdgcn_perm(__builtin_bit_cast(uint32, (HI)), \
                                          __builtin_bit_cast(uint32, (LO)), 0x07060302u)

// ---------------- Phase 1 (fused): Krylov chains + Horner + MFMA GEMM + pack ----------------
// (bit-identical to R14's kernel)
__global__ __launch_bounds__(1024) void k_build(const float* __restrict__ Araw,
                                                const float* __restrict__ Bv,
                                                const float* __restrict__ Cv,
                                                uint2* __restrict__ Rqg) {
    __shared__ float sm[39168];           // 156,672 B
    float* kry = sm;                      // [NW][256] = 3840
    float* red = sm + 3840;               // [2][4][256] = 2048 (double-buffered)
    float* Wl  = sm + 5888;               // [64][260] padded = 16640
    float* Vt  = sm + 22528;              // [64][260] padded (V transposed) = 16640
    float* Kf  = sm;                      // 4096, aliases kry+red[0][0..255] (dead)

    const int tid = threadIdx.x;
    const int j = tid & 255, seg = tid >> 8, lane = tid & 63;
    const int e = 64 * seg + lane;        // this thread's vv element
    float a[64];

#define DOT64(S0, S1, VV) { \
    _Pragma("unroll") \
    for (int m = 0; m < 64; m += 2) { \
        S0 = fmaf(rdlane(VV, m), a[m], S0); \
        S1 = fmaf(rdlane(VV, m + 1), a[m + 1], S1); \
    } }

    // ---- W-chain: a[m] = A[64seg+m][j] (coalesced over j) ----
#pragma unroll
    for (int m = 0; m < 64; ++m) a[m] = Araw[(64 * seg + m) * 256 + j];
    if (tid < 256) kry[tid] = Cv[tid];
    __syncthreads();
    const float WSC = 4032.0f / 4096.0f;
    {
        float vv = kry[e];
        for (int n = 1; n < NW; ++n) {
            float s0 = 0.f, s1 = 0.f;
            DOT64(s0, s1, vv)
            float* rb = red + (n & 1) * 1024;
            rb[seg * 256 + j] = s0 + s1;
            __syncthreads();
            float sc = WSC / (float)n;
            vv = (rb[e] + rb[256 + e] + rb[512 + e] + rb[768 + e]) * sc;
            if (tid < 256)
                kry[n * 256 + tid] = (rb[tid] + rb[256 + tid] + rb[512 + tid] + rb[768 + tid]) * sc;
        }
    }
    __syncthreads();
    {   // Horner -> Wl[q][j], stride 260
        float kj[NW];
#pragma unroll
        for (int n = 0; n < NW; ++n) kj[n] = kry[n * 256 + j];
#pragma unroll
        for (int u = 0; u < 16; ++u) {
            int q = seg + 4 * u;
            float c = (float)q * (1.0f / 63.0f);
            float h = kj[NW - 1];
#pragma unroll
            for (int n = NW - 2; n >= 0; --n) h = fmaf(c, h, kj[n]);
            Wl[q * 260 + j] = h;
        }
    }

    // ---- reload a as row-strips: a[m] = A[j][64seg+m] ----
    {
        const float4* Ar = (const float4*)(Araw + (size_t)j * 256 + 64 * seg);
#pragma unroll
        for (int m4 = 0; m4 < 16; ++m4) {
            float4 q4 = Ar[m4];
            a[4 * m4] = q4.x; a[4 * m4 + 1] = q4.y; a[4 * m4 + 2] = q4.z; a[4 * m4 + 3] = q4.w;
        }
    }
    // ---- Bbar Neumann (3 rounds, Bv in-register), then V-chain ----
    const float ms = 0.5f * STEPF;
    const float bve = Bv[e];
    {
        float vv = bve;
        for (int it = 0; it < 3; ++it) {
            float s0 = 0.f, s1 = 0.f;
            DOT64(s0, s1, vv)
            float* rb = red + (it & 1) * 1024;
            rb[seg * 256 + j] = s0 + s1;
            __syncthreads();
            vv = fmaf(ms, rb[e] + rb[256 + e] + rb[512 + e] + rb[768 + e], bve);
            if (it == 2 && tid < 256) {
                float su = rb[tid] + rb[256 + tid] + rb[512 + tid] + rb[768 + tid];
                kry[tid] = STEPF * fmaf(ms, su, Bv[tid]);
            }
        }
    }
    __syncthreads();
    const float VSC = 63.0f / 4096.0f;
    {
        float vv = kry[e];
        for (int n = 1; n < NV; ++n) {
            float s0 = 0.f, s1 = 0.f;
            DOT64(s0, s1, vv)
            float* rb = red + (n & 1) * 1024;
            rb[seg * 256 + j] = s0 + s1;
            __syncthreads();
            float sc = VSC / (float)n;
            vv = (rb[e] + rb[256 + e] + rb[512 + e] + rb[768 + e]) * sc;
            if (tid < 256)
                kry[n * 256 + tid] = (rb[tid] + rb[256 + tid] + rb[512 + tid] + rb[768 + tid]) * sc;
        }
    }
    __syncthreads();
    {   // Horner -> Vt[r][j] (transposed, stride 260)
        float kj[NV];
#pragma unroll
        for (int n = 0; n < NV; ++n) kj[n] = kry[n * 256 + j];
#pragma unroll
        for (int u = 0; u < 16; ++u) {
            int r = seg + 4 * u;
            float c = (float)r * (1.0f / 63.0f);
            float h = kj[NV - 1];
#pragma unroll
            for (int n = NV - 2; n >= 0; --n) h = fmaf(c, h, kj[n]);
            Vt[r * 260 + j] = h;
        }
    }
    __syncthreads();   // Wl, Vt complete; kry/red dead

    // ---- MFMA GEMM: Kf[64q + r] = sum_k Wl[q][k] * Vt[r][k] ----
    {
        const int wv = tid >> 6;
        const int qt = wv >> 2, rt = wv & 3;
        const int n16 = lane & 15, g4 = lane >> 4;
        const int q = 16 * qt + n16;
        const int r = 16 * rt + n16;
        f32x4 ac = (f32x4){0.f, 0.f, 0.f, 0.f};
        for (int s = 0; s < 8; ++s) {
            const int kk = 32 * s + 8 * g4;
            float4 w0 = *(const float4*)&Wl[q * 260 + kk];
            float4 w1 = *(const float4*)&Wl[q * 260 + kk + 4];
            float4 v0 = *(const float4*)&Vt[r * 260 + kk];
            float4 v1 = *(const float4*)&Vt[r * 260 + kk + 4];
            uint4 uh; uh.x = PK2(w0.x, w0.y); uh.y = PK2(w0.z, w0.w);
                      uh.z = PK2(w1.x, w1.y); uh.w = PK2(w1.z, w1.w);
            float l0 = w0.x - hif(w0.x), l1 = w0.y - hif(w0.y);
            float l2 = w0.z - hif(w0.z), l3 = w0.w - hif(w0.w);
            float l4 = w1.x - hif(w1.x), l5 = w1.y - hif(w1.y);
            float l6 = w1.z - hif(w1.z), l7 = w1.w - hif(w1.w);
            uint4 ul; ul.x = PK2(l0, l1); ul.y = PK2(l2, l3);
                      ul.z = PK2(l4, l5); ul.w = PK2(l6, l7);
            uint4 uv; uv.x = PK2(v0.x, v0.y); uv.y = PK2(v0.z, v0.w);
                      uv.z = PK2(v1.x, v1.y); uv.w = PK2(v1.z, v1.w);
            ac = __builtin_amdgcn_mfma_f32_16x16x32_bf16(__builtin_bit_cast(bf16x8, uh),
                                                         __builtin_bit_cast(bf16x8, uv), ac, 0, 0, 0);
            ac = __builtin_amdgcn_mfma_f32_16x16x32_bf16(__builtin_bit_cast(bf16x8, ul),
                                                         __builtin_bit_cast(bf16x8, uv), ac, 0, 0, 0);
        }
#pragma unroll
        for (int jj = 0; jj < 4; ++jj)
            Kf[(16 * qt + 4 * g4 + jj) * 64 + r] = ac[jj];
    }
    __syncthreads();

    // ---- pack reversed-K quad table to global ----
    for (int i = tid; i < RQN; i += 1024) {
        int aa = 4095 - i;
        uint32 e0 = (aa >= 0) ? bf16rne(Kf[aa]) : 0u;
        uint32 e1 = (aa >= 1) ? bf16rne(Kf[aa - 1]) : 0u;
        uint32 e2 = (aa >= 2) ? bf16rne(Kf[aa - 2]) : 0u;
        uint32 e3 = (aa >= 3) ? bf16rne(Kf[aa - 3]) : 0u;
        uint2 v; v.x = e0 | (e1 << 16); v.y = e2 | (e3 << 16);
        Rqg[i] = v;
    }
#undef DOT64
}

// ---------------- Phase 2: MFMA causal conv, T=8, 4 waves/SIMD, j-split ----------------
// Out[d,t] = sum_j y[d,j] K[t-j].  512-thread blocks = 8 waves = (ds 4 d-subtiles
// of 16 rows) x (jh 2 j-halves).  32 t-strips of 128 cols; block runs strip pair
// (31-by, by): per-wave steps = 2(32-by) + 2(by+1) = 66, constant.  Grid (32,16)
// = 512 blocks = 2/CU = 16 waves/CU = 4 waves/SIMD -> heterogeneous stall phases
// overlap (the R9-R15 plateau was phase-locked stalls at <=2 waves/SIMD).
// T=8 keeps per-wave state ~100 VGPR (<=128 needed for 4/SIMD).
__global__ __launch_bounds__(512, 4) void k_conv(const uint2* __restrict__ Rqg,
                                                 const float* __restrict__ y,
                                                 const float* __restrict__ Dp,
                                                 float* __restrict__ out) {
    __shared__ uint2 Rq[RQN];
    __shared__ f32x4 mbuf[4][8][64];   // [ds][acc-idx][lane]
    const int tid = threadIdx.x;
#pragma unroll
    for (int i = 0; i < RQN / 512; ++i) Rq[i * 512 + tid] = Rqg[i * 512 + tid];
    __syncthreads();

    const int w = tid >> 6, lane = tid & 63;
    const int n = lane & 15, g = lane >> 4;
    const int ds = w & 3, jh = w >> 2;
    const int by = (int)blockIdx.y;                   // 0..15
    const int d0w = (int)blockIdx.x * 64 + ds * 16;
    const int d = d0w + n;
    const float4* __restrict__ yq = (const float4*)(y + (size_t)d * L_);
    const float D0 = Dp[0];

#define LOADF(SL, I0) { \
    uint2 u0 = Rq[(I0)]; uint2 u1 = Rq[(I0) + 4]; \
    uint4 uu; uu.x = u0.x; uu.y = u0.y; uu.z = u1.x; uu.w = u1.y; \
    fr[SL] = __builtin_bit_cast(bf16x8, uu); }
#define PACKAV(Q0, Q1) { \
    uint4 ua; ua.x = PK2((Q0).x, (Q0).y); ua.y = PK2((Q0).z, (Q0).w); \
    ua.z = PK2((Q1).x, (Q1).y); ua.w = PK2((Q1).z, (Q1).w); \
    av = __builtin_bit_cast(bf16x8, ua); }
#define MF(TI, SL) acc[TI] = __builtin_amdgcn_mfma_f32_16x16x32_bf16(av, fr[SL], acc[TI], 0, 0, 0);

// Even/odd steps consume + refill opposite y-buffer pairs (prefetch depth 2).
#define STEPE(YI, S0,S1,S2,S3,S4,S5,S6,S7) { \
    PACKAV(q0a, q0b); \
    MF(6, S6) MF(7, S7) \
    LOADF(S6, bcur + 32) LOADF(S7, bcur + 16) \
    q0a = yq[(YI)]; q0b = yq[(YI) + 1]; \
    yn += 8; bcur += 32; \
    MF(0,S0) MF(1,S1) MF(2,S2) MF(3,S3) MF(4,S4) MF(5,S5) \
}
#define STEPO(YI, S0,S1,S2,S3,S4,S5,S6,S7) { \
    PACKAV(q1a, q1b); \
    MF(6, S6) MF(7, S7) \
    LOADF(S6, bcur + 32) LOADF(S7, bcur + 16) \
    q1a = yq[(YI)]; q1b = yq[(YI) + 1]; \
    yn += 8; bcur += 32; \
    MF(0,S0) MF(1,S1) MF(2,S2) MF(3,S3) MF(4,S4) MF(5,S5) \
}

#define ROUND4(YIM) \
    STEPE(YIM, 0,1,2,3,4,5,6,7) \
    STEPO(YIM, 6,7,0,1,2,3,4,5) \
    STEPE(YIM, 4,5,6,7,0,1,2,3) \
    STEPO(YIM, 2,3,4,5,6,7,0,1)

    for (int strip = 0; strip < 2; ++strip) {
        const int v = strip ? by : (31 - by);
        const int t0 = v << 7;
        const int Sh = 2 * (v + 1);       // per-wave j-steps (half of strip total)
        const int s0 = jh * Sh;           // starting j-chunk

        f32x4 acc[8];
#pragma unroll
        for (int i = 0; i < 8; ++i) acc[i] = (f32x4){0.f, 0.f, 0.f, 0.f};
        bf16x8 fr[8], av;
        float4 q0a, q0b, q1a, q1b;

        const int B0 = 4095 - t0 - n + 8 * g + 32 * s0;
#pragma unroll
        for (int ti = 0; ti < 8; ++ti) LOADF(ti, B0 - 16 * ti)
        q0a = yq[8 * s0 + 2 * g];     q0b = yq[8 * s0 + 2 * g + 1];     // step s0
        q1a = yq[8 * s0 + 8 + 2 * g]; q1b = yq[8 * s0 + 8 + 2 * g + 1]; // step s0+1
        int bcur = B0;
        int yn = 8 * s0 + 16 + 2 * g;   // float4 index of y prefetch, 2 steps ahead

        const int nfull = Sh >> 2;
        for (int it = 0; it < nfull - 1; ++it) {
            ROUND4(yn)
        }
        if (nfull > 0) {
            // clamp y prefetch in the last full round (only jh=1 of v=31 can run OOB)
            ROUND4(yn < 1016 ? yn : 1016)
        }
        if (Sh & 2) {   // 2-step tail (v even); never approaches row end
            STEPE(yn, 0,1,2,3,4,5,6,7)
            STEPO(yn, 6,7,0,1,2,3,4,5)
        }

        // ---- merge j-halves via LDS, then jh=0 stores ----
        if (jh == 1) {
#pragma unroll
            for (int i = 0; i < 8; ++i) mbuf[ds][i][lane] = acc[i];
        }
        __syncthreads();
        if (jh == 0) {
#pragma unroll
            for (int i = 0; i < 8; ++i) {
                f32x4 m = mbuf[ds][i][lane];
                acc[i][0] += m[0]; acc[i][1] += m[1];
                acc[i][2] += m[2]; acc[i][3] += m[3];
            }
        }
        __syncthreads();
        if (jh == 0) {
#pragma unroll
            for (int ti = 0; ti < 8; ++ti) {
                int tcol = t0 + 16 * ti + n;
#pragma unroll
                for (int r = 0; r < 4; ++r) {
                    int dr = d0w + 4 * g + r;
                    size_t ix = (size_t)dr * L_ + tcol;
                    out[ix] = acc[ti][r] + D0 * y[ix];
                }
            }
        }
    }

#undef ROUND4
#undef STEPE
#undef STEPO
#undef MF
#undef PACKAV
#undef LOADF
}

// ---------------- host ----------------

extern "C" void kernel_launch(void* const* d_in, const int* in_sizes, int n_in,
                              void* d_out, int out_size, void* d_ws, size_t ws_size,
                              hipStream_t stream) {
    const float* y  = (const float*)d_in[0];
    const float* A  = (const float*)d_in[1];
    const float* Bv = (const float*)d_in[2];
    const float* Cv = (const float*)d_in[3];
    const float* Dp = (const float*)d_in[4];
    float* out = (float*)d_out;
    uint2* Rqg = (uint2*)d_ws;   // 4608 quads (36,864 B)

    k_build<<<dim3(1), dim3(1024), 0, stream>>>(A, Bv, Cv, Rqg);
    k_conv<<<dim3(32, 16), dim3(512), 0, stream>>>(Rqg, y, Dp, out);

    (void)in_sizes; (void)n_in; (void)out_size; (void)ws_size;
}

// Round 17
// 68.312 us; speedup vs baseline: 1.5702x; 1.5702x over previous
//
#include <hip/hip_runtime.h>

#define N_ 256
#define L_ 4096
#define DM_ 2048
#define STEPF (1.0f / 4096.0f)
#define NW 10   // W-side Taylor: tail 2^10/10! ~ 2.8e-4 rel << bf16-K quant (4e-3)
#define NV 5    // V-side Taylor: 0.031^5/5! ~ 2e-10
#define RQN 4608

typedef short bf16x8 __attribute__((ext_vector_type(8)));
typedef float f32x4 __attribute__((ext_vector_type(4)));
typedef unsigned int uint32;

__device__ __forceinline__ uint32 bf16rne(float f) {
    uint32 u = __builtin_bit_cast(uint32, f);
    return (u + 0x7FFFu + ((u >> 16) & 1u)) >> 16;
}
__device__ __forceinline__ float rdlane(float v, int l) {
    return __builtin_bit_cast(float, __builtin_amdgcn_readlane(__builtin_bit_cast(int, v), l));
}
__device__ __forceinline__ float hif(float x) {   // bf16-truncated high part
    return __builtin_bit_cast(float, __builtin_bit_cast(uint32, x) & 0xFFFF0000u);
}
// pack 2 f32 -> 2 bf16 (truncate) in one v_perm: dst = {LO.hi16, HI.hi16}
#define PK2(LO, HI) __builtin_amdgcn_perm(__builtin_bit_cast(uint32, (HI)), \
                                          __builtin_bit_cast(uint32, (LO)), 0x07060302u)

// ---------------- Phase 1 (fused): build K (block 0) + pack y->bf16 (blocks 1..256) ----------------
// Block 0: Krylov chains + Horner + hi/lo-split MFMA GEMM + reversed-K pack (R14 structure,
// trimmed NW/NV/Neumann).  Blocks 1..256: convert y (f32) -> ybf (bf16, truncate) for the
// conv A-operand; runs CONCURRENTLY with block 0 on other CUs (zero added serial time).
__global__ __launch_bounds__(1024) void k_build(const float* __restrict__ Araw,
                                                const float* __restrict__ Bv,
                                                const float* __restrict__ Cv,
                                                const float* __restrict__ yf,
                                                uint2* __restrict__ Rqg,
                                                uint4* __restrict__ ybf) {
    const int tid = threadIdx.x;
    if (blockIdx.x > 0) {
        // ---- y pack: 256 blocks x 1024 thr x 4 iters x 8 floats = 8,388,608 elems ----
        const size_t base = (size_t)(blockIdx.x - 1) * 32768;   // elems
        const float4* yin = (const float4*)(yf + base);
        uint4* yo = ybf + base / 8;
#pragma unroll
        for (int i = 0; i < 4; ++i) {
            int c = i * 1024 + tid;            // chunk of 8 floats
            float4 q0 = yin[2 * c], q1 = yin[2 * c + 1];
            uint4 o; o.x = PK2(q0.x, q0.y); o.y = PK2(q0.z, q0.w);
                     o.z = PK2(q1.x, q1.y); o.w = PK2(q1.z, q1.w);
            yo[c] = o;
        }
        return;
    }

    __shared__ float sm[39168];           // 156,672 B
    float* kry = sm;                      // [NW][256]
    float* red = sm + 3840;               // [2][4][256] double-buffered
    float* Wl  = sm + 5888;               // [64][260] padded
    float* Vt  = sm + 22528;              // [64][260] padded (V transposed)
    float* Kf  = sm;                      // 4096, aliases kry (dead by then)

    const int j = tid & 255, seg = tid >> 8, lane = tid & 63;
    const int e = 64 * seg + lane;
    float a[64];

#define DOT64(S0, S1, VV) { \
    _Pragma("unroll") \
    for (int m = 0; m < 64; m += 2) { \
        S0 = fmaf(rdlane(VV, m), a[m], S0); \
        S1 = fmaf(rdlane(VV, m + 1), a[m + 1], S1); \
    } }

    // ---- W-chain: a[m] = A[64seg+m][j] ----
#pragma unroll
    for (int m = 0; m < 64; ++m) a[m] = Araw[(64 * seg + m) * 256 + j];
    if (tid < 256) kry[tid] = Cv[tid];
    __syncthreads();
    const float WSC = 4032.0f / 4096.0f;
    {
        float vv = kry[e];
        for (int n = 1; n < NW; ++n) {
            float s0 = 0.f, s1 = 0.f;
            DOT64(s0, s1, vv)
            float* rb = red + (n & 1) * 1024;
            rb[seg * 256 + j] = s0 + s1;
            __syncthreads();
            float sc = WSC / (float)n;
            vv = (rb[e] + rb[256 + e] + rb[512 + e] + rb[768 + e]) * sc;
            if (tid < 256)
                kry[n * 256 + tid] = (rb[tid] + rb[256 + tid] + rb[512 + tid] + rb[768 + tid]) * sc;
        }
    }
    __syncthreads();
    {   // Horner -> Wl[q][j], stride 260
        float kj[NW];
#pragma unroll
        for (int n = 0; n < NW; ++n) kj[n] = kry[n * 256 + j];
#pragma unroll
        for (int u = 0; u < 16; ++u) {
            int q = seg + 4 * u;
            float c = (float)q * (1.0f / 63.0f);
            float h = kj[NW - 1];
#pragma unroll
            for (int n = NW - 2; n >= 0; --n) h = fmaf(c, h, kj[n]);
            Wl[q * 260 + j] = h;
        }
    }

    // ---- reload a as row-strips: a[m] = A[j][64seg+m] ----
    {
        const float4* Ar = (const float4*)(Araw + (size_t)j * 256 + 64 * seg);
#pragma unroll
        for (int m4 = 0; m4 < 16; ++m4) {
            float4 q4 = Ar[m4];
            a[4 * m4] = q4.x; a[4 * m4 + 1] = q4.y; a[4 * m4 + 2] = q4.z; a[4 * m4 + 3] = q4.w;
        }
    }
    // ---- Bbar Neumann (2 rounds; residual (2.4e-4)^2), then V-chain ----
    const float ms = 0.5f * STEPF;
    const float bve = Bv[e];
    {
        float vv = bve;
        for (int it = 0; it < 2; ++it) {
            float s0 = 0.f, s1 = 0.f;
            DOT64(s0, s1, vv)
            float* rb = red + (it & 1) * 1024;
            rb[seg * 256 + j] = s0 + s1;
            __syncthreads();
            vv = fmaf(ms, rb[e] + rb[256 + e] + rb[512 + e] + rb[768 + e], bve);
            if (it == 1 && tid < 256) {
                float su = rb[tid] + rb[256 + tid] + rb[512 + tid] + rb[768 + tid];
                kry[tid] = STEPF * fmaf(ms, su, Bv[tid]);
            }
        }
    }
    __syncthreads();
    const float VSC = 63.0f / 4096.0f;
    {
        float vv = kry[e];
        for (int n = 1; n < NV; ++n) {
            float s0 = 0.f, s1 = 0.f;
            DOT64(s0, s1, vv)
            float* rb = red + (n & 1) * 1024;
            rb[seg * 256 + j] = s0 + s1;
            __syncthreads();
            float sc = VSC / (float)n;
            vv = (rb[e] + rb[256 + e] + rb[512 + e] + rb[768 + e]) * sc;
            if (tid < 256)
                kry[n * 256 + tid] = (rb[tid] + rb[256 + tid] + rb[512 + tid] + rb[768 + tid]) * sc;
        }
    }
    __syncthreads();
    {   // Horner -> Vt[r][j] (transposed, stride 260)
        float kj[NV];
#pragma unroll
        for (int n = 0; n < NV; ++n) kj[n] = kry[n * 256 + j];
#pragma unroll
        for (int u = 0; u < 16; ++u) {
            int r = seg + 4 * u;
            float c = (float)r * (1.0f / 63.0f);
            float h = kj[NV - 1];
#pragma unroll
            for (int n = NV - 2; n >= 0; --n) h = fmaf(c, h, kj[n]);
            Vt[r * 260 + j] = h;
        }
    }
    __syncthreads();   // Wl, Vt complete; kry/red dead

    // ---- MFMA GEMM: Kf[64q + r] = sum_k Wl[q][k] * Vt[r][k] (W hi/lo split) ----
    {
        const int wv = tid >> 6;
        const int qt = wv >> 2, rt = wv & 3;
        const int n16 = lane & 15, g4 = lane >> 4;
        const int q = 16 * qt + n16;
        const int r = 16 * rt + n16;
        f32x4 ac = (f32x4){0.f, 0.f, 0.f, 0.f};
        for (int s = 0; s < 8; ++s) {
            const int kk = 32 * s + 8 * g4;
            float4 w0 = *(const float4*)&Wl[q * 260 + kk];
            float4 w1 = *(const float4*)&Wl[q * 260 + kk + 4];
            float4 v0 = *(const float4*)&Vt[r * 260 + kk];
            float4 v1 = *(const float4*)&Vt[r * 260 + kk + 4];
            uint4 uh; uh.x = PK2(w0.x, w0.y); uh.y = PK2(w0.z, w0.w);
                      uh.z = PK2(w1.x, w1.y); uh.w = PK2(w1.z, w1.w);
            float l0 = w0.x - hif(w0.x), l1 = w0.y - hif(w0.y);
            float l2 = w0.z - hif(w0.z), l3 = w0.w - hif(w0.w);
            float l4 = w1.x - hif(w1.x), l5 = w1.y - hif(w1.y);
            float l6 = w1.z - hif(w1.z), l7 = w1.w - hif(w1.w);
            uint4 ul; ul.x = PK2(l0, l1); ul.y = PK2(l2, l3);
                      ul.z = PK2(l4, l5); ul.w = PK2(l6, l7);
            uint4 uv; uv.x = PK2(v0.x, v0.y); uv.y = PK2(v0.z, v0.w);
                      uv.z = PK2(v1.x, v1.y); uv.w = PK2(v1.z, v1.w);
            ac = __builtin_amdgcn_mfma_f32_16x16x32_bf16(__builtin_bit_cast(bf16x8, uh),
                                                         __builtin_bit_cast(bf16x8, uv), ac, 0, 0, 0);
            ac = __builtin_amdgcn_mfma_f32_16x16x32_bf16(__builtin_bit_cast(bf16x8, ul),
                                                         __builtin_bit_cast(bf16x8, uv), ac, 0, 0, 0);
        }
#pragma unroll
        for (int jj = 0; jj < 4; ++jj)
            Kf[(16 * qt + 4 * g4 + jj) * 64 + r] = ac[jj];
    }
    __syncthreads();

    // ---- pack reversed-K quad table to global ----
    for (int i = tid; i < RQN; i += 1024) {
        int aa = 4095 - i;
        uint32 e0 = (aa >= 0) ? bf16rne(Kf[aa]) : 0u;
        uint32 e1 = (aa >= 1) ? bf16rne(Kf[aa - 1]) : 0u;
        uint32 e2 = (aa >= 2) ? bf16rne(Kf[aa - 2]) : 0u;
        uint32 e3 = (aa >= 3) ? bf16rne(Kf[aa - 3]) : 0u;
        uint2 v; v.x = e0 | (e1 << 16); v.y = e2 | (e3 << 16);
        Rqg[i] = v;
    }
#undef DOT64
}

// ---------------- Phase 2: MFMA causal conv, T=16, j-split, direct-bf16 A-frags ----------------
// R11/R14 structure (proven 47 us), y path replaced: A-frag = ONE dwordx4 from pre-packed
// ybf (16B = the exact 8-bf16 fragment).  Removes PACKAV (4 v_perm) + 4-float4 shuffles,
// halves y-load instrs and bytes; ybf is 2 MB/XCD -> L2-resident.  No setprio (R15: null).
__global__ __launch_bounds__(256, 2) void k_conv(const uint2* __restrict__ Rqg,
                                                 const uint4* __restrict__ ybf,
                                                 const float* __restrict__ y,
                                                 const float* __restrict__ Dp,
                                                 float* __restrict__ out) {
    __shared__ uint2 Rq[RQN];
    __shared__ f32x4 mbuf[2][8][64];   // [ds][acc-idx][lane]
    const int tid = threadIdx.x;
#pragma unroll
    for (int i = 0; i < RQN / 256; ++i) Rq[i * 256 + tid] = Rqg[i * 256 + tid];
    __syncthreads();

    const int w = tid >> 6, lane = tid & 63;
    const int n = lane & 15, g = lane >> 4;
    const int ds = w & 1, jh = w >> 1;
    const int by = (int)blockIdx.y;                   // 0..7
    const int d0w = (int)blockIdx.x * 32 + ds * 16;
    const int d = d0w + n;
    const uint4* __restrict__ ybr = ybf + (size_t)d * (L_ / 8);   // 512 uint4 per row
    const float D0 = Dp[0];

#define LOADF(SL, I0) { \
    uint2 u0 = Rq[(I0)]; uint2 u1 = Rq[(I0) + 4]; \
    uint4 uu; uu.x = u0.x; uu.y = u0.y; uu.z = u1.x; uu.w = u1.y; \
    fr[SL] = __builtin_bit_cast(bf16x8, uu); }
#define MF(TI, SL) acc[TI] = __builtin_amdgcn_mfma_f32_16x16x32_bf16(av, fr[SL], acc[TI], 0, 0, 0);

// Even/odd steps consume + refill opposite av buffers (prefetch depth 2).
// y index masked &511 (always in-row; overrun values unused).
#define STEPE(S0,S1,S2,S3,S4,S5,S6,S7,S8,S9,S10,S11,S12,S13,S14,S15) { \
    av = __builtin_bit_cast(bf16x8, ave); \
    MF(14, S14) MF(15, S15) \
    LOADF(S14, bcur + 32) LOADF(S15, bcur + 16) \
    ave = ybr[yn & 511]; \
    yn += 4; bcur += 32; \
    MF(0,S0) MF(1,S1) MF(2,S2) MF(3,S3) MF(4,S4) MF(5,S5) MF(6,S6) MF(7,S7) \
    MF(8,S8) MF(9,S9) MF(10,S10) MF(11,S11) MF(12,S12) MF(13,S13) \
}
#define STEPO(S0,S1,S2,S3,S4,S5,S6,S7,S8,S9,S10,S11,S12,S13,S14,S15) { \
    av = __builtin_bit_cast(bf16x8, avo); \
    MF(14, S14) MF(15, S15) \
    LOADF(S14, bcur + 32) LOADF(S15, bcur + 16) \
    avo = ybr[yn & 511]; \
    yn += 4; bcur += 32; \
    MF(0,S0) MF(1,S1) MF(2,S2) MF(3,S3) MF(4,S4) MF(5,S5) MF(6,S6) MF(7,S7) \
    MF(8,S8) MF(9,S9) MF(10,S10) MF(11,S11) MF(12,S12) MF(13,S13) \
}

#define ROUND8() \
    STEPE(0,1,2,3,4,5,6,7,8,9,10,11,12,13,14,15) \
    STEPO(14,15,0,1,2,3,4,5,6,7,8,9,10,11,12,13) \
    STEPE(12,13,14,15,0,1,2,3,4,5,6,7,8,9,10,11) \
    STEPO(10,11,12,13,14,15,0,1,2,3,4,5,6,7,8,9) \
    STEPE(8,9,10,11,12,13,14,15,0,1,2,3,4,5,6,7) \
    STEPO(6,7,8,9,10,11,12,13,14,15,0,1,2,3,4,5) \
    STEPE(4,5,6,7,8,9,10,11,12,13,14,15,0,1,2,3) \
    STEPO(2,3,4,5,6,7,8,9,10,11,12,13,14,15,0,1)

#define ROUND4() \
    STEPE(0,1,2,3,4,5,6,7,8,9,10,11,12,13,14,15) \
    STEPO(14,15,0,1,2,3,4,5,6,7,8,9,10,11,12,13) \
    STEPE(12,13,14,15,0,1,2,3,4,5,6,7,8,9,10,11) \
    STEPO(10,11,12,13,14,15,0,1,2,3,4,5,6,7,8,9)

    for (int strip = 0; strip < 2; ++strip) {
        const int v = strip ? by : (15 - by);
        const int t0 = v << 8;
        const int Sh = 4 * (v + 1);       // per-wave j-steps (half of strip total)
        const int s0 = jh * Sh;           // starting j-chunk (even)

        f32x4 acc[16];
#pragma unroll
        for (int i = 0; i < 16; ++i) acc[i] = (f32x4){0.f, 0.f, 0.f, 0.f};
        bf16x8 fr[16], av;
        uint4 ave, avo;

        const int B0 = 4095 - t0 - n + 8 * g + 32 * s0;
#pragma unroll
        for (int ti = 0; ti < 16; ++ti) LOADF(ti, B0 - 16 * ti)
        ave = ybr[4 * s0 + g];            // step s0
        avo = ybr[4 * s0 + 4 + g];        // step s0+1
        int bcur = B0;
        int yn = 4 * s0 + 8 + g;          // uint4 index of y prefetch, 2 steps ahead

        const int n8 = Sh >> 3;
        for (int it = 0; it < n8; ++it) {
            ROUND8()
        }
        if (Sh & 4) {
            ROUND4()
        }

        // ---- merge j-halves (2 conflict-free LDS rounds), then jh=0 stores ----
#pragma unroll
        for (int rr = 0; rr < 2; ++rr) {
            if (jh == 1) {
#pragma unroll
                for (int i = 0; i < 8; ++i) mbuf[ds][i][lane] = acc[rr * 8 + i];
            }
            __syncthreads();
            if (jh == 0) {
#pragma unroll
                for (int i = 0; i < 8; ++i) {
                    f32x4 m = mbuf[ds][i][lane];
                    acc[rr * 8 + i][0] += m[0]; acc[rr * 8 + i][1] += m[1];
                    acc[rr * 8 + i][2] += m[2]; acc[rr * 8 + i][3] += m[3];
                }
            }
            __syncthreads();
        }
        if (jh == 0) {
#pragma unroll
            for (int ti = 0; ti < 16; ++ti) {
                int tcol = t0 + 16 * ti + n;
#pragma unroll
                for (int r = 0; r < 4; ++r) {
                    int dr = d0w + 4 * g + r;
                    size_t ix = (size_t)dr * L_ + tcol;
                    out[ix] = acc[ti][r] + D0 * y[ix];   // D-term stays f32
                }
            }
        }
    }

#undef ROUND8
#undef ROUND4
#undef STEPE
#undef STEPO
#undef MF
#undef LOADF
}

// ---------------- host ----------------

extern "C" void kernel_launch(void* const* d_in, const int* in_sizes, int n_in,
                              void* d_out, int out_size, void* d_ws, size_t ws_size,
                              hipStream_t stream) {
    const float* y  = (const float*)d_in[0];
    const float* A  = (const float*)d_in[1];
    const float* Bv = (const float*)d_in[2];
    const float* Cv = (const float*)d_in[3];
    const float* Dp = (const float*)d_in[4];
    float* out = (float*)d_out;
    char* w = (char*)d_ws;
    uint2* Rqg = (uint2*)w;                       // 36,864 B
    uint4* ybf = (uint4*)(w + 36864);             // 16,777,216 B (2048x4096 bf16)

    k_build<<<dim3(257), dim3(1024), 0, stream>>>(A, Bv, Cv, y, Rqg, ybf);
    k_conv<<<dim3(64, 8), dim3(256), 0, stream>>>(Rqg, ybf, y, Dp, out);

    (void)in_sizes; (void)n_in; (void)out_size; (void)ws_size;
}